// Round 11
// baseline (1131.933 us; speedup 1.0000x reference)
//
#include <hip/hip_runtime.h>
#include <stdint.h>

#define T_ 512
#define B_ 32
#define V_ 512
#define L_ 128
#define NEGF (-1000000000.0f)

// Signed-i8 quantization: E = exp(trans) in ~[0.55,1.83]; SE*1.83 < 127.
#define SE_Q 69.0f
#define SU_Q 127.0f
#define LOGC 9.078313f   /* log(SE_Q * SU_Q) */

typedef int v4i __attribute__((ext_vector_type(4)));

// monotonic float<->uint for LDS atomicMax
__device__ __forceinline__ unsigned fkey(float f) {
    unsigned u = __float_as_uint(f);
    return (u & 0x80000000u) ? ~u : (u | 0x80000000u);
}
__device__ __forceinline__ float funkey(unsigned k) {
    unsigned u = (k & 0x80000000u) ? (k ^ 0x80000000u) : ~k;
    return __uint_as_float(u);
}

// ---------------- prep: quantize E into MFMA A-fragment layout (R9/R10
// verbatim — hardware-validated, absmax 0.0) ---------------------------------
// asg_main thread tid: w=tid>>6, lane=tid&63, q=lane>>4, n=lane&15.
// Wave w owns rows 64w..64w+63 as 4 M-tiles (tt) x 8 K-tiles (kt).
// A-frag (tt,kt): lane holds A[m=64w+16tt+n][k=64kt+16q+4d+b].
__global__ void asg_prep(const float* __restrict__ trans, uint32_t* __restrict__ Et) {
    int o = blockIdx.x * blockDim.x + threadIdx.x;      // 0 .. 65535
    int d    = o & 3;
    int tid  = (o >> 2) & 511;
    int qreg = o >> 11;                                  // 0..31
    int tt = qreg >> 3, kt = qreg & 7;
    int w = tid >> 6, lane = tid & 63;
    int q = lane >> 4, n = lane & 15;
    int m  = 64 * w + 16 * tt + n;
    int k0 = 64 * kt + 16 * q + 4 * d;
    const float* tp = trans + (size_t)m * V_ + k0;
    uint32_t q0 = (uint32_t)fminf(127.0f, __expf(tp[0]) * SE_Q + 0.5f);
    uint32_t q1 = (uint32_t)fminf(127.0f, __expf(tp[1]) * SE_Q + 0.5f);
    uint32_t q2 = (uint32_t)fminf(127.0f, __expf(tp[2]) * SE_Q + 0.5f);
    uint32_t q3 = (uint32_t)fminf(127.0f, __expf(tp[3]) * SE_Q + 0.5f);
    Et[(size_t)o] = q0 | (q1 << 8) | (q2 << 16) | (q3 << 24);
}

// ---------------- fused main: blocks 0,1 = FCC(16 batches each); 2..33 = FAC -
// R10 structure + three fixes: lp software-pipelined across the step (latency
// hidden under MFMA + barriers), atomicMax depth 32->8 via __shfl_xor(16,32),
// alpha freeze-in-place instead of fin[] (VGPR-neutral prefetch).
__global__ __attribute__((amdgpu_flat_work_group_size(512, 512),
                          amdgpu_waves_per_eu(2, 2)))
void asg_main(
    const float* __restrict__ lp, const uint32_t* __restrict__ Et,
    const float* __restrict__ trans, const int* __restrict__ targets,
    const int* __restrict__ ilen, const int* __restrict__ tlen,
    float* __restrict__ fcc_ws, float* __restrict__ fac_ws)
{
    __shared__ float facb[256];                       // fac double buffer
    __shared__ __align__(16) uint32_t u_lds[2048];    // 16 batches x 512 u8
    __shared__ unsigned mslot[2][16];
    __shared__ unsigned mslotE[16];
    __shared__ float    sumfv[16];
    __shared__ int      tmax_sh;

    const int bb  = blockIdx.x;
    const int tid = threadIdx.x;

    if (bb < 2) {
        // ================= FCC: 16 batches ================================
        const int bbase = bb * 16;
        const int lane  = tid & 63;
        const int w     = tid >> 6;             // wave 0..7: rows 64w..64w+63
        const int q     = lane >> 4;            // 0..3
        const int n     = lane & 15;            // batch column
        const int bg    = bbase + n;            // this lane's batch
        const int myT   = ilen[bg];

        // loop-invariant LDS offsets (validated swizzle: <=2-way aliasing)
        int woff[4], boff[8];
        #pragma unroll
        for (int tt = 0; tt < 4; ++tt)
            woff[tt] = n * 128 + ((4 * w + tt + 3 * n) & 31) * 4 + q;
        #pragma unroll
        for (int kt = 0; kt < 8; ++kt)
            boff[kt] = (n * 32 + ((4 * kt + q + 3 * n) & 31)) * 4;
        const float* lpbase = lp + (size_t)bg * V_ + 64 * w + 4 * q;

        // er: 32 uint4 A-frags (validated no-spill path, shared by batches)
        uint4 er4[32];
        {
            const uint4* Eq = (const uint4*)Et;
            #pragma unroll
            for (int t8 = 0; t8 < 32; ++t8) er4[t8] = Eq[t8 * 512 + tid];
        }

        // alpha_0 = lp[0][bg][64w+16tt+4q+rg]
        float alpha[16], lpv[16];
        #pragma unroll
        for (int tt = 0; tt < 4; ++tt) {
            float4 v = *(const float4*)(lpbase + 16 * tt);
            alpha[4 * tt + 0] = v.x; alpha[4 * tt + 1] = v.y;
            alpha[4 * tt + 2] = v.z; alpha[4 * tt + 3] = v.w;
        }

        if (tid < 16) {
            mslot[0][tid] = 0u; mslot[1][tid] = 0u;
            mslotE[tid] = 0u; sumfv[tid] = 0.0f;
        }
        if (tid == 0) tmax_sh = 0;
        __syncthreads();
        atomicMax(&tmax_sh, myT);        // 16 distinct values; cheap once
        __syncthreads();
        const int Tmax = tmax_sh;

        // preload lp for t=1 (waits once at first alpha update)
        {
            int t1 = (Tmax > 1) ? 1 : 0;
            #pragma unroll
            for (int tt = 0; tt < 4; ++tt) {
                float4 v = *(const float4*)(lpbase + (size_t)t1 * (B_ * V_) + 16 * tt);
                lpv[4 * tt + 0] = v.x; lpv[4 * tt + 1] = v.y;
                lpv[4 * tt + 2] = v.z; lpv[4 * tt + 3] = v.w;
            }
        }

        for (int t = 1; t < Tmax; ++t) {
            // ---- phase A: per-batch block max; q-reduce first (depth 8)
            {
                float mx = alpha[0];
                #pragma unroll
                for (int j = 1; j < 16; ++j) mx = fmaxf(mx, alpha[j]);
                mx = fmaxf(mx, __shfl_xor(mx, 16));
                mx = fmaxf(mx, __shfl_xor(mx, 32));
                if (q == 0) atomicMax(&mslot[(t - 1) & 1][n], fkey(mx));
            }
            __syncthreads();                        // [max visible]
            const float m = funkey(mslot[(t - 1) & 1][n]);

            // ---- phase B: u8 publish (swizzled), slot reset
            #pragma unroll
            for (int tt = 0; tt < 4; ++tt) {
                uint32_t q0 = (uint32_t)(__expf(alpha[4 * tt + 0] - m) * SU_Q + 0.5f);
                uint32_t q1 = (uint32_t)(__expf(alpha[4 * tt + 1] - m) * SU_Q + 0.5f);
                uint32_t q2 = (uint32_t)(__expf(alpha[4 * tt + 2] - m) * SU_Q + 0.5f);
                uint32_t q3 = (uint32_t)(__expf(alpha[4 * tt + 3] - m) * SU_Q + 0.5f);
                u_lds[woff[tt]] = q0 | (q1 << 8) | (q2 << 16) | (q3 << 24);
            }
            if (tid < 16) mslot[t & 1][tid] = 0u;
            __syncthreads();                        // [u visible]

            // ---- prefetch next lp (in flight across MFMA + next barrier)
            float lpn[16];
            {
                int tn = (t + 1 < Tmax) ? (t + 1) : t;
                #pragma unroll
                for (int tt = 0; tt < 4; ++tt) {
                    float4 v = *(const float4*)(lpbase + (size_t)tn * (B_ * V_) + 16 * tt);
                    lpn[4 * tt + 0] = v.x; lpn[4 * tt + 1] = v.y;
                    lpn[4 * tt + 2] = v.z; lpn[4 * tt + 3] = v.w;
                }
            }

            // ---- phase C: 8 B-frags, 32 MFMA, alpha update (freeze past myT)
            v4i a0, a1, a2, a3;
            { v4i z = {0, 0, 0, 0}; a0 = z; a1 = z; a2 = z; a3 = z; }
            #pragma unroll
            for (int kt = 0; kt < 8; ++kt) {
                uint4 bf = *(const uint4*)&u_lds[boff[kt]];
                v4i bv = __builtin_bit_cast(v4i, bf);
                a0 = __builtin_amdgcn_mfma_i32_16x16x64_i8(
                        __builtin_bit_cast(v4i, er4[0 * 8 + kt]), bv, a0, 0, 0, 0);
                a1 = __builtin_amdgcn_mfma_i32_16x16x64_i8(
                        __builtin_bit_cast(v4i, er4[1 * 8 + kt]), bv, a1, 0, 0, 0);
                a2 = __builtin_amdgcn_mfma_i32_16x16x64_i8(
                        __builtin_bit_cast(v4i, er4[2 * 8 + kt]), bv, a2, 0, 0, 0);
                a3 = __builtin_amdgcn_mfma_i32_16x16x64_i8(
                        __builtin_bit_cast(v4i, er4[3 * 8 + kt]), bv, a3, 0, 0, 0);
            }
            const float mc = m - LOGC;
            const bool upd = (t < myT);
            alpha[0]  = upd ? (lpv[0]  + mc + __logf((float)a0.x)) : alpha[0];
            alpha[1]  = upd ? (lpv[1]  + mc + __logf((float)a0.y)) : alpha[1];
            alpha[2]  = upd ? (lpv[2]  + mc + __logf((float)a0.z)) : alpha[2];
            alpha[3]  = upd ? (lpv[3]  + mc + __logf((float)a0.w)) : alpha[3];
            alpha[4]  = upd ? (lpv[4]  + mc + __logf((float)a1.x)) : alpha[4];
            alpha[5]  = upd ? (lpv[5]  + mc + __logf((float)a1.y)) : alpha[5];
            alpha[6]  = upd ? (lpv[6]  + mc + __logf((float)a1.z)) : alpha[6];
            alpha[7]  = upd ? (lpv[7]  + mc + __logf((float)a1.w)) : alpha[7];
            alpha[8]  = upd ? (lpv[8]  + mc + __logf((float)a2.x)) : alpha[8];
            alpha[9]  = upd ? (lpv[9]  + mc + __logf((float)a2.y)) : alpha[9];
            alpha[10] = upd ? (lpv[10] + mc + __logf((float)a2.z)) : alpha[10];
            alpha[11] = upd ? (lpv[11] + mc + __logf((float)a2.w)) : alpha[11];
            alpha[12] = upd ? (lpv[12] + mc + __logf((float)a3.x)) : alpha[12];
            alpha[13] = upd ? (lpv[13] + mc + __logf((float)a3.y)) : alpha[13];
            alpha[14] = upd ? (lpv[14] + mc + __logf((float)a3.z)) : alpha[14];
            alpha[15] = upd ? (lpv[15] + mc + __logf((float)a3.w)) : alpha[15];

            #pragma unroll
            for (int j = 0; j < 16; ++j) lpv[j] = lpn[j];
        }

        // ---- epilogue: per-batch exact f32 logsumexp over frozen alpha
        {
            float mx = alpha[0];
            #pragma unroll
            for (int j = 1; j < 16; ++j) mx = fmaxf(mx, alpha[j]);
            mx = fmaxf(mx, __shfl_xor(mx, 16));
            mx = fmaxf(mx, __shfl_xor(mx, 32));
            if (q == 0) atomicMax(&mslotE[n], fkey(mx));
        }
        __syncthreads();
        {
            float m2 = funkey(mslotE[n]);
            float s = 0.0f;
            #pragma unroll
            for (int j = 0; j < 16; ++j) s += __expf(alpha[j] - m2);
            s += __shfl_xor(s, 16);
            s += __shfl_xor(s, 32);
            if (q == 0) atomicAdd(&sumfv[n], s);
        }
        __syncthreads();
        if (tid < 16)
            fcc_ws[bbase + tid] = funkey(mslotE[tid]) + __logf(sumfv[tid]);
    } else {
        // ================= FAC (threads 0..127 active) =====================
        const int b = bb - 2;
        const int l = tid;
        const bool active = (l < L_);
        const int Tlen = ilen[b];
        const int Llen = tlen[b];

        const int tl  = active ? targets[b * L_ + l] : 0;
        const int tlm = (active && l > 0) ? targets[b * L_ + l - 1] : 0;
        const float ts = active ? trans[(size_t)tl * V_ + tl] : 0.0f;
        const float tp = (active && l > 0) ? trans[(size_t)tl * V_ + tlm] : 0.0f;

        float beta = (l == 0) ? lp[(size_t)b * V_ + tl] : NEGF;
        float em_next = active ? lp[(size_t)1 * (B_ * V_) + (size_t)b * V_ + tl] : 0.0f;

        for (int t = 1; t < Tlen; ++t) {
            float* buf = facb + (t & 1) * L_;
            if (active) buf[l] = beta;
            __syncthreads();
            float prev = (active && l > 0) ? buf[l - 1] : NEGF;
            float em = em_next;
            if (active && t + 1 < Tlen)
                em_next = lp[(size_t)(t + 1) * (B_ * V_) + (size_t)b * V_ + tl];
            if (active) {
                float st = beta + ts;
                float mv = prev + tp;
                float mx = fmaxf(st, mv);
                float mn = fminf(st, mv);
                beta = em + mx + log1pf(__expf(mn - mx));
            }
        }
        if (active && l == Llen - 1) fac_ws[b] = beta;
    }
}

// ---------------- combine ---------------------------------------------------
__global__ void asg_combine(const float* __restrict__ fcc_ws,
                            const float* __restrict__ fac_ws,
                            float* __restrict__ out) {
    int i = threadIdx.x;
    if (i < B_) out[i] = fcc_ws[i] - fac_ws[i];
}

extern "C" void kernel_launch(void* const* d_in, const int* in_sizes, int n_in,
                              void* d_out, int out_size, void* d_ws, size_t ws_size,
                              hipStream_t stream) {
    const float* lp      = (const float*)d_in[0];
    const float* trans   = (const float*)d_in[1];
    const int*   targets = (const int*)d_in[2];
    const int*   ilen    = (const int*)d_in[3];
    const int*   tlen    = (const int*)d_in[4];
    float* out = (float*)d_out;

    uint32_t* Et     = (uint32_t*)d_ws;                    // 65536 dwords = 256 KB
    float*    fcc_ws = (float*)((char*)d_ws + 65536 * 4);
    float*    fac_ws = fcc_ws + B_;

    hipLaunchKernelGGL(asg_prep, dim3(256), dim3(256), 0, stream, trans, Et);
    hipLaunchKernelGGL(asg_main, dim3(2 + B_), dim3(512), 0, stream,
                       lp, Et, trans, targets, ilen, tlen, fcc_ws, fac_ws);
    hipLaunchKernelGGL(asg_combine, dim3(1), dim3(64), 0, stream, fcc_ws, fac_ws, out);
}

// Round 12
// 719.894 us; speedup vs baseline: 1.5724x; 1.5724x over previous
//
#include <hip/hip_runtime.h>
#include <stdint.h>

#define T_ 512
#define B_ 32
#define V_ 512
#define L_ 128
#define NEGF (-1000000000.0f)

// Signed-i8 quantization: E = exp(trans) in ~[0.55,1.83]; SE*1.83 < 127.
#define SE_Q 69.0f
#define SU_Q 127.0f
#define LOGC 9.078313f   /* log(SE_Q * SU_Q) */

typedef int v4i __attribute__((ext_vector_type(4)));

template <int CTRL>
__device__ __forceinline__ int dppmov(int old_, int src) {
    return __builtin_amdgcn_update_dpp(old_, src, CTRL, 0xF, 0xF, false);
}
// monotonic float<->uint for LDS atomicMax
__device__ __forceinline__ unsigned fkey(float f) {
    unsigned u = __float_as_uint(f);
    return (u & 0x80000000u) ? ~u : (u | 0x80000000u);
}
__device__ __forceinline__ float funkey(unsigned k) {
    unsigned u = (k & 0x80000000u) ? (k ^ 0x80000000u) : ~k;
    return __uint_as_float(u);
}
__device__ __forceinline__ float rlf(int vi, int l) {
    return __int_as_float(__builtin_amdgcn_readlane(vi, l));
}
// select element r (0..3) of v4i
__device__ __forceinline__ int sel4(v4i a, int r) {
    int x0 = (r & 1) ? a.y : a.x;
    int x1 = (r & 1) ? a.w : a.z;
    return (r & 2) ? x1 : x0;
}

// ---------------- prep: quantize E into MFMA A-fragment layout --------------
// asg_main thread tid (1024 thr): w=tid>>6, lane=tid&63, q=lane>>4, n=lane&15.
// Wave w owns rows 32w..32w+31 as 2 M-tiles (tt) x 8 K-tiles (kt).
// A-frag (tt,kt): lane holds A[m=32w+16tt+n][k=64kt+16q+4d+b] (R9-validated
// intra-tile mapping, new tile bases). er4[qreg=tt*8+kt]=Eq[qreg*1024+tid].
__global__ void asg_prep(const float* __restrict__ trans, uint32_t* __restrict__ Et) {
    int o = blockIdx.x * blockDim.x + threadIdx.x;      // 0 .. 65535
    int d    = o & 3;
    int tid  = (o >> 2) & 1023;
    int qreg = o >> 12;                                  // 0..15
    int tt = qreg >> 3, kt = qreg & 7;
    int w = tid >> 6, lane = tid & 63;
    int q = lane >> 4, n = lane & 15;
    int m  = 32 * w + 16 * tt + n;
    int k0 = 64 * kt + 16 * q + 4 * d;
    const float* tp = trans + (size_t)m * V_ + k0;
    uint32_t q0 = (uint32_t)fminf(127.0f, __expf(tp[0]) * SE_Q + 0.5f);
    uint32_t q1 = (uint32_t)fminf(127.0f, __expf(tp[1]) * SE_Q + 0.5f);
    uint32_t q2 = (uint32_t)fminf(127.0f, __expf(tp[2]) * SE_Q + 0.5f);
    uint32_t q3 = (uint32_t)fminf(127.0f, __expf(tp[3]) * SE_Q + 0.5f);
    Et[(size_t)o] = q0 | (q1 << 8) | (q2 << 16) | (q3 << 24);
}

// ---------------- fused main: blocks 0..15 = FCC(2 batches); 16..47 = FAC ---
// FCC: cols 0-7 = batch 2f, cols 8-15 = batch 2f+1. Lane (q,n): batch=n>>3,
// tile=(n>>2)&1, reg=n&3 -> owns row 32w+16tt+4q+rg of its batch (exactly one
// (batch,row) per lane; scalar head = 1 exp + 1 log, as R9). 16 waves =
// 4 waves/SIMD for latency hiding; er = 64 dwords -> no spill at 128-reg cap.
__global__ __attribute__((amdgpu_flat_work_group_size(1024, 1024),
                          amdgpu_waves_per_eu(4, 4)))
void asg_main(
    const float* __restrict__ lp, const uint32_t* __restrict__ Et,
    const float* __restrict__ trans, const int* __restrict__ targets,
    const int* __restrict__ ilen, const int* __restrict__ tlen,
    float* __restrict__ fcc_ws, float* __restrict__ fac_ws)
{
    __shared__ float facb[256];                       // fac double buffer
    __shared__ __align__(16) uint32_t u_lds[256];     // 2 batches x u8[512]
    __shared__ unsigned mslot[2][2];                  // [buf][batch]
    __shared__ unsigned mslotE[2];
    __shared__ float    sumfv[2];
    __shared__ int      tmax_sh;

    const int bb  = blockIdx.x;
    const int tid = threadIdx.x;

    if (bb < 16) {
        // ================= FCC: 2 batches =================================
        const int f    = bb;
        const int lane = tid & 63;
        const int w    = tid >> 6;             // wave 0..15: rows 32w..32w+31
        const int q    = lane >> 4;            // 0..3
        const int n    = lane & 15;            // col
        const int bsel = n >> 3;               // batch within block
        const int bg   = 2 * f + bsel;         // global batch
        const int tt_o = (n >> 2) & 1;
        const int rg_o = n & 3;
        const int row  = 32 * w + 16 * tt_o + 4 * q + rg_o;
        const int myT  = ilen[bg];

        // er: 16 uint4 A-frags, lane-coalesced one-time load
        uint4 er4[16];
        {
            const uint4* Eq = (const uint4*)Et;
            #pragma unroll
            for (int qreg = 0; qreg < 16; ++qreg) er4[qreg] = Eq[qreg * 1024 + tid];
        }

        float alpha = lp[(size_t)bg * V_ + row];

        if (tid < 2) {
            mslot[0][tid] = 0u; mslot[1][tid] = 0u;
            mslotE[tid] = 0u; sumfv[tid] = 0.0f;
        }
        if (tid == 0) tmax_sh = 0;
        __syncthreads();
        if (lane == 0 || lane == 8) atomicMax(&tmax_sh, myT);
        __syncthreads();
        const int Tmax = tmax_sh;

        for (int t = 1; t < Tmax; ++t) {
            const int buf = (t - 1) & 1;
            // ---- phase A: per-batch wave max (bits {0,1,2}; batch=bit3 kept)
            {
                float v = alpha;
                int vi = __float_as_int(v);
                v = fmaxf(v, __int_as_float(dppmov<0xB1>(vi, vi))); vi = __float_as_int(v);
                v = fmaxf(v, __int_as_float(dppmov<0x4E>(vi, vi))); vi = __float_as_int(v);
                v = fmaxf(v, __int_as_float(__builtin_amdgcn_ds_swizzle(vi, 0x101F)));
                vi = __float_as_int(v);
                float m0 = fmaxf(fmaxf(rlf(vi, 0), rlf(vi, 16)),
                                 fmaxf(rlf(vi, 32), rlf(vi, 48)));
                float m1 = fmaxf(fmaxf(rlf(vi, 8), rlf(vi, 24)),
                                 fmaxf(rlf(vi, 40), rlf(vi, 56)));
                if (lane == 0) atomicMax(&mslot[buf][0], fkey(m0));
                if (lane == 8) atomicMax(&mslot[buf][1], fkey(m1));
            }
            __syncthreads();                           // [max visible]
            const float m = funkey(mslot[buf][bsel]);

            // ---- phase B: u8 publish (quad-pack over rg via DPP), lp load
            {
                float u = __expf(alpha - m);           // <= 1
                uint32_t qu = (uint32_t)(u * SU_Q + 0.5f);
                int pv = (int)(qu << (8 * rg_o));      // rg_o == lane bits 0-1
                pv |= dppmov<0xB1>(pv, pv);
                pv |= dppmov<0x4E>(pv, pv);
                if (rg_o == 0)
                    u_lds[bsel * 128 + 8 * w + 4 * tt_o + q] = (uint32_t)pv;
            }
            float lpv = lp[(size_t)t * (B_ * V_) + (size_t)bg * V_ + row];
            if (tid == 0) { mslot[t & 1][0] = 0u; mslot[t & 1][1] = 0u; }
            __syncthreads();                           // [u visible]

            // ---- phase C: 8 B-frags (own batch's u), 16 MFMA, alpha update
            v4i a0, a1;
            { v4i z = {0, 0, 0, 0}; a0 = z; a1 = z; }
            const char* ub = (const char*)u_lds + bsel * 512;
            #pragma unroll
            for (int kt = 0; kt < 8; ++kt) {
                uint4 bf = *(const uint4*)(ub + 64 * kt + 16 * q);
                v4i bv = __builtin_bit_cast(v4i, bf);
                a0 = __builtin_amdgcn_mfma_i32_16x16x64_i8(
                        __builtin_bit_cast(v4i, er4[0 * 8 + kt]), bv, a0, 0, 0, 0);
                a1 = __builtin_amdgcn_mfma_i32_16x16x64_i8(
                        __builtin_bit_cast(v4i, er4[1 * 8 + kt]), bv, a1, 0, 0, 0);
            }
            v4i asel;
            asel.x = tt_o ? a1.x : a0.x;  asel.y = tt_o ? a1.y : a0.y;
            asel.z = tt_o ? a1.z : a0.z;  asel.w = tt_o ? a1.w : a0.w;
            int acc = sel4(asel, rg_o);

            float na = lpv + (m - LOGC) + __logf((float)acc);
            alpha = (t < myT) ? na : alpha;            // freeze past myT
        }

        // ---- epilogue: per-batch exact f32 logsumexp
        {
            float v = alpha;
            int vi = __float_as_int(v);
            v = fmaxf(v, __int_as_float(dppmov<0xB1>(vi, vi))); vi = __float_as_int(v);
            v = fmaxf(v, __int_as_float(dppmov<0x4E>(vi, vi))); vi = __float_as_int(v);
            v = fmaxf(v, __int_as_float(__builtin_amdgcn_ds_swizzle(vi, 0x101F)));
            vi = __float_as_int(v);
            float m0 = fmaxf(fmaxf(rlf(vi, 0), rlf(vi, 16)),
                             fmaxf(rlf(vi, 32), rlf(vi, 48)));
            float m1 = fmaxf(fmaxf(rlf(vi, 8), rlf(vi, 24)),
                             fmaxf(rlf(vi, 40), rlf(vi, 56)));
            if (lane == 0) atomicMax(&mslotE[0], fkey(m0));
            if (lane == 8) atomicMax(&mslotE[1], fkey(m1));
        }
        __syncthreads();
        {
            const float m2 = funkey(mslotE[bsel]);
            float s = __expf(alpha - m2);
            int si = __float_as_int(s);
            s = s + __int_as_float(dppmov<0xB1>(si, si)); si = __float_as_int(s);
            s = s + __int_as_float(dppmov<0x4E>(si, si)); si = __float_as_int(s);
            s = s + __int_as_float(__builtin_amdgcn_ds_swizzle(si, 0x101F));
            si = __float_as_int(s);
            float s0 = rlf(si, 0) + rlf(si, 16) + rlf(si, 32) + rlf(si, 48);
            float s1 = rlf(si, 8) + rlf(si, 24) + rlf(si, 40) + rlf(si, 56);
            if (lane == 0) atomicAdd(&sumfv[0], s0);
            if (lane == 8) atomicAdd(&sumfv[1], s1);
        }
        __syncthreads();
        if (tid == 0) fcc_ws[2 * f]     = funkey(mslotE[0]) + __logf(sumfv[0]);
        if (tid == 8) fcc_ws[2 * f + 1] = funkey(mslotE[1]) + __logf(sumfv[1]);
    } else {
        // ================= FAC (threads 0..127 active) =====================
        const int b = bb - 16;
        const int l = tid;
        const bool active = (l < L_);
        const int Tlen = ilen[b];
        const int Llen = tlen[b];

        const int tl  = active ? targets[b * L_ + l] : 0;
        const int tlm = (active && l > 0) ? targets[b * L_ + l - 1] : 0;
        const float ts = active ? trans[(size_t)tl * V_ + tl] : 0.0f;
        const float tp = (active && l > 0) ? trans[(size_t)tl * V_ + tlm] : 0.0f;

        float beta = (l == 0) ? lp[(size_t)b * V_ + tl] : NEGF;
        float em_next = active ? lp[(size_t)1 * (B_ * V_) + (size_t)b * V_ + tl] : 0.0f;

        for (int t = 1; t < Tlen; ++t) {
            float* buf = facb + (t & 1) * L_;
            if (active) buf[l] = beta;
            __syncthreads();
            float prev = (active && l > 0) ? buf[l - 1] : NEGF;
            float em = em_next;
            if (active && t + 1 < Tlen)
                em_next = lp[(size_t)(t + 1) * (B_ * V_) + (size_t)b * V_ + tl];
            if (active) {
                float st = beta + ts;
                float mv = prev + tp;
                float mx = fmaxf(st, mv);
                float mn = fminf(st, mv);
                beta = em + mx + log1pf(__expf(mn - mx));
            }
        }
        if (active && l == Llen - 1) fac_ws[b] = beta;
    }
}

// ---------------- combine ---------------------------------------------------
__global__ void asg_combine(const float* __restrict__ fcc_ws,
                            const float* __restrict__ fac_ws,
                            float* __restrict__ out) {
    int i = threadIdx.x;
    if (i < B_) out[i] = fcc_ws[i] - fac_ws[i];
}

extern "C" void kernel_launch(void* const* d_in, const int* in_sizes, int n_in,
                              void* d_out, int out_size, void* d_ws, size_t ws_size,
                              hipStream_t stream) {
    const float* lp      = (const float*)d_in[0];
    const float* trans   = (const float*)d_in[1];
    const int*   targets = (const int*)d_in[2];
    const int*   ilen    = (const int*)d_in[3];
    const int*   tlen    = (const int*)d_in[4];
    float* out = (float*)d_out;

    uint32_t* Et     = (uint32_t*)d_ws;                    // 65536 dwords = 256 KB
    float*    fcc_ws = (float*)((char*)d_ws + 65536 * 4);
    float*    fac_ws = fcc_ws + B_;

    hipLaunchKernelGGL(asg_prep, dim3(256), dim3(256), 0, stream, trans, Et);
    hipLaunchKernelGGL(asg_main, dim3(16 + B_), dim3(1024), 0, stream,
                       lp, Et, trans, targets, ilen, tlen, fcc_ws, fac_ws);
    hipLaunchKernelGGL(asg_combine, dim3(1), dim3(64), 0, stream, fcc_ws, fac_ws, out);
}